// Round 14
// baseline (846.279 us; speedup 1.0000x reference)
//
#include <hip/hip_runtime.h>
#include <stdint.h>

// LTC encoder B=256,T=1024,F=64,H=128. One WG per batch row, NT=512.
// R22 = R21 + B's hn0-GEMV software-pipelined one phase ahead (symmetric
// to A's R21 change). B shifts to j = p-3: hn0[j+1] is barrier-visible
// during phase p (A published it at phase j+2 = p-1), so at the BOTTOM of
// phase p B runs the 8 Wx1/Wt1 MFMAs for its next step into 2 carried
// scalars -> off the pa-chain; they overlap B's tail + barrier wait on
// the matrix pipe. B's top chain: stats1/h1 ds_read -> 4 Wh1 MFMAs
// (split 2x2-deep) -> tail. 1027 phases; ring audit: hn0p slot s written
// p=s+1, overwritten p=s+5, B's piped read at p=s+2, A's same-phase write
// slot differs ✓; stats1 slot read at p, overwritten p+4 ✓.
// R21 post-mortem: A's identical treatment gave 875->834 (-5%), MFMA 36.5
// VALU 42.8 (79% busy); B now phase-critical with 12 top-of-phase MFMAs.
// Base (verified R20/R21): A publishes hn0; per-wave-slot stats; lgkm-only
// wg_barrier; 8 waves, 32 cols/wave via two 16x16x32 tiles; gamma-folded
// self-recurrence weights; A's x-GEMV pipelined.

#define B_ 256
#define T_ 1024
#define F_ 64
#define H_ 128
#define EPS_ 1e-5f
#define NT_ 512

typedef _Float16 h2 __attribute__((ext_vector_type(2)));
typedef _Float16 h8 __attribute__((ext_vector_type(8)));
typedef float f32x4 __attribute__((ext_vector_type(4)));
typedef __fp16  f16v2 __attribute__((ext_vector_type(2)));

__device__ __forceinline__ h2 pkf16(float a, float b) {
  union { f16v2 f; h2 h; } c;
  c.f = __builtin_amdgcn_cvt_pkrtz(a, b);
  return c.h;
}
__device__ __forceinline__ uint32_t as_u32(h2 h) { union { h2 h; uint32_t u; } c; c.h = h; return c.u; }

// workgroup barrier WITHOUT vmcnt drain: LDS ops complete (lgkmcnt),
// global loads stay in flight across the barrier.
__device__ __forceinline__ void wg_barrier() {
  asm volatile("s_waitcnt lgkmcnt(0)\n\ts_barrier" ::: "memory");
}

#if __has_builtin(__builtin_amdgcn_rsqf)
__device__ __forceinline__ float rsq_fast(float x) { return __builtin_amdgcn_rsqf(x); }
#else
__device__ __forceinline__ float rsq_fast(float x) { return rsqrtf(x); }
#endif

// 16-lane sum via DPP row_ror (every lane of each 16-row gets the row sum).
#if __has_builtin(__builtin_amdgcn_update_dpp)
template <int CTRL>
__device__ __forceinline__ float dpp_add(float v) {
  union { float f; int i; } a, b;
  a.f = v;
  b.i = __builtin_amdgcn_update_dpp(0, a.i, CTRL, 0xf, 0xf, true);
  return v + b.f;
}
__device__ __forceinline__ float red16(float v) {
  v = dpp_add<0x128>(v);   // row_ror:8
  v = dpp_add<0x124>(v);   // row_ror:4
  v = dpp_add<0x122>(v);   // row_ror:2
  v = dpp_add<0x121>(v);   // row_ror:1
  return v;
}
#else
__device__ __forceinline__ float red16(float v) {
  v += __shfl_xor(v, 1); v += __shfl_xor(v, 2);
  v += __shfl_xor(v, 4); v += __shfl_xor(v, 8);
  return v;
}
#endif

// pack 8 consecutive fp32 weights into one MFMA half-fragment (4 VGPRs)
__device__ __forceinline__ h8 packfrag(const float* p) {
  float4 a = *(const float4*)p;
  float4 b = *(const float4*)(p + 4);
  union { h2 h[4]; h8 v; } c;
  c.h[0] = pkf16(a.x, a.y); c.h[1] = pkf16(a.z, a.w);
  c.h[2] = pkf16(b.x, b.y); c.h[3] = pkf16(b.z, b.w);
  return c.v;
}
// load 8 fp32 weights, fold LN-gamma into the k-dim, accumulate Sum(w*g)
// (= sum of folded values) and Sum(w*be); return folded frag as f16.
__device__ __forceinline__ h8 packfrag_g(const float* w, const float* gv, const float* bv,
                                         float& dg, float& dbe) {
  float4 a = *(const float4*)w;
  float4 b = *(const float4*)(w + 4);
  float4 ga = *(const float4*)gv;
  float4 gb = *(const float4*)(gv + 4);
  float4 ba = *(const float4*)bv;
  float4 bb = *(const float4*)(bv + 4);
  float w0 = a.x*ga.x, w1 = a.y*ga.y, w2 = a.z*ga.z, w3 = a.w*ga.w;
  float w4 = b.x*gb.x, w5 = b.y*gb.y, w6 = b.z*gb.z, w7 = b.w*gb.w;
  dg  += (w0 + w1) + (w2 + w3) + (w4 + w5) + (w6 + w7);
  dbe += a.x*ba.x + a.y*ba.y + a.z*ba.z + a.w*ba.w
       + b.x*bb.x + b.y*bb.y + b.z*bb.z + b.w*bb.w;
  union { h2 h[4]; h8 v; } c;
  c.h[0] = pkf16(w0, w1); c.h[1] = pkf16(w2, w3);
  c.h[2] = pkf16(w4, w5); c.h[3] = pkf16(w6, w7);
  return c.v;
}
// broadcast A-fragment from packed-f16 LDS (16B per lane-group, conflict-free)
__device__ __forceinline__ h8 ldfrag(const uint32_t* p) {
  union { uint4 u; h8 v; } c;
  c.u = *(const uint4*)p;
  return c.v;
}

__device__ __forceinline__ float tanh_fast(float a) {
  float aa = fabsf(a);
  float e  = __expf(2.f * aa);
  float th = 1.f - 2.f * __builtin_amdgcn_rcpf(e + 1.f);
  return copysignf(th, a);
}
__device__ __forceinline__ float softplus_fast(float x) {
  return (x > 20.f) ? x : __logf(1.f + __expf(x));
}

#define MFMA16(A_, B_, C_) __builtin_amdgcn_mfma_f32_16x16x32_f16(A_, B_, C_, 0, 0, 0)

__global__ void __attribute__((amdgpu_flat_work_group_size(NT_, NT_)))
                __attribute__((amdgpu_waves_per_eu(2, 2)))
ltc_scan(
    const float* __restrict__ x,
    const float* __restrict__ Wh0, const float* __restrict__ bh0,
    const float* __restrict__ Wx0, const float* __restrict__ bx0,
    const float* __restrict__ Wt0, const float* __restrict__ bt0,
    const float* __restrict__ tau0, const float* __restrict__ g0,
    const float* __restrict__ be0,
    const float* __restrict__ Wh1, const float* __restrict__ bh1,
    const float* __restrict__ Wx1, const float* __restrict__ bx1,
    const float* __restrict__ Wt1, const float* __restrict__ bt1,
    const float* __restrict__ tau1, const float* __restrict__ g1,
    const float* __restrict__ be1,
    float* __restrict__ out)
{
  __shared__ __align__(16) uint32_t h0p[2][64];   // hc0 raw, A-only dbuf
  __shared__ __align__(16) uint32_t h1p[2][64];   // hc1 raw, B-only dbuf
  __shared__ __align__(16) uint32_t hn0p[4][64];  // hn0[i] = LN(hc0[i]), 4-ring
  __shared__ __align__(16) uint32_t x4[4][32];    // x[t] packed f16, 4-ring
  __shared__ __align__(16) float2   p0s[4][4];    // L0 stats [slot][wave]{s,s2}
  __shared__ __align__(16) float2   p1s[4][4];    // L1 stats

  const int tid = threadIdx.x;
  const int wid = tid >> 6;
  const int l   = tid & 63;
  const int g4  = (l >> 4) << 2;    // LDS u32 offset of this dup-group's frag
  const int g8  = (l >> 4) << 3;    // k offset (floats) of this dup-group
  const int b   = blockIdx.x;
  const float* xg = x + (size_t)b * (T_ * F_);
  const bool selT1 = (l & 16) != 0; // lanes 16-31 / 48-63 serve tile 1

  if (tid < 128) { ((uint32_t*)h0p)[tid] = 0u; ((uint32_t*)h1p)[tid] = 0u; }
  if (tid < 32)  { ((float*)p0s)[tid] = 0.f; ((float*)p1s)[tid] = 0.f; }
  if (tid < 32) {                   // stage x[0], x[1]
    float2 a = *(const float2*)(xg + 2 * tid);
    float2 c = *(const float2*)(xg + F_ + 2 * tid);
    x4[0][tid] = as_u32(pkf16(a.x, a.y));
    x4[1][tid] = as_u32(pkf16(c.x, c.y));
  }
  __syncthreads();                  // one full barrier at start (drains init)

  if (wid < 4) {
    // ========== group A: layer 0, step i = p; cols wid*32 .. +31 ==========
    const int c0 = wid * 32 + (l & 15);
    const int ct = wid * 32 + (l & 31);
    h8 wh0[4], wh1[4], wx0[2], wx1[2], wt0[2], wt1[2];
    float cg, cb;
    {
      float dg0 = 0.f, db0 = 0.f, dg1 = 0.f, db1 = 0.f;
      const float* p0 = Wh0 + c0 * H_ + g8;
      const float* p1 = Wh0 + (c0 + 16) * H_ + g8;
      #pragma unroll
      for (int m = 0; m < 4; ++m) {
        wh0[m] = packfrag_g(p0 + 32 * m, g0 + g8 + 32 * m, be0 + g8 + 32 * m, dg0, db0);
        wh1[m] = packfrag_g(p1 + 32 * m, g0 + g8 + 32 * m, be0 + g8 + 32 * m, dg1, db1);
      }
      dg0 += __shfl_xor(dg0, 16); dg0 += __shfl_xor(dg0, 32);
      db0 += __shfl_xor(db0, 16); db0 += __shfl_xor(db0, 32);
      dg1 += __shfl_xor(dg1, 16); dg1 += __shfl_xor(dg1, 32);
      db1 += __shfl_xor(db1, 16); db1 += __shfl_xor(db1, 32);
      cg = selT1 ? dg1 : dg0; cb = selT1 ? db1 : db0;
      const float* q0 = Wx0 + c0 * F_ + g8;
      const float* q1 = Wx0 + (c0 + 16) * F_ + g8;
      const float* r0 = Wt0 + c0 * F_ + g8;
      const float* r1 = Wt0 + (c0 + 16) * F_ + g8;
      #pragma unroll
      for (int m = 0; m < 2; ++m) {
        wx0[m] = packfrag(q0 + 32 * m); wx1[m] = packfrag(q1 + 32 * m);
        wt0[m] = packfrag(r0 + 32 * m); wt1[m] = packfrag(r1 + 32 * m);
      }
    }
    const float bhx = bh0[ct] + bx0[ct];
    const float btr = bt0[ct], taub = tau0[ct], gr = g0[ct], ber = be0[ct];
    const int  widx = wid * 16 + ((l & 31) >> 1);
    const bool wlane = ((l & 33) == 0);
    const bool st = (wid == 0) && (l < 32);

    float hcp = 0.f;
    float2 xc0, xc1;                 // distance-2 x prefetch
    if (st) {
      xc0 = *(const float2*)(xg + 2 * F_ + 2 * l);
      xc1 = *(const float2*)(xg + 3 * F_ + 2 * l);
    }
    // prologue: x-contributions for step 0 (from x4[0], staged at init)
    float xcs, tcs;
    {
      const uint32_t* xb = x4[0];
      f32x4 nX0 = {0.f,0.f,0.f,0.f}, nX1 = {0.f,0.f,0.f,0.f};
      f32x4 nT0 = {0.f,0.f,0.f,0.f}, nT1 = {0.f,0.f,0.f,0.f};
      #pragma unroll
      for (int m = 0; m < 2; ++m) {
        h8 xf = ldfrag(xb + m * 16 + g4);
        nX0 = MFMA16(xf, wx0[m], nX0);
        nX1 = MFMA16(xf, wx1[m], nX1);
        nT0 = MFMA16(xf, wt0[m], nT0);
        nT1 = MFMA16(xf, wt1[m], nT1);
      }
      xcs = (selT1 ? nX1[0] : nX0[0]) + bhx;
      tcs = (selT1 ? nT1[0] : nT0[0]) + btr;
    }

    #pragma unroll 4
    for (int p = 0; p <= T_ + 2; ++p) {
      if (p <= T_) {
        const int i = p;
        const float4* sp = (const float4*)&p0s[(i + 3) & 3][0];  // stats0[i-1]
        float4 sa = sp[0], sb = sp[1];
        float ss  = (sa.x + sa.z) + (sb.x + sb.z);
        float s2s = (sa.y + sa.w) + (sb.y + sb.w);
        if (st) {                    // write x[i+2]; issue load of x[i+4]
          x4[(i + 2) & 3][l] = as_u32(pkf16(xc0.x, xc0.y));
          xc0 = xc1;
          int tn = (i + 4 < T_) ? (i + 4) : (T_ - 1);
          xc1 = *(const float2*)(xg + tn * F_ + 2 * l);
        }
        const uint32_t* ub = h0p[(i + 1) & 1];     // hc0[i-1]
        // Wh chain: 4 independent 2-deep chains
        f32x4 aH0a = {0.f,0.f,0.f,0.f}, aH0b = {0.f,0.f,0.f,0.f};
        f32x4 aH1a = {0.f,0.f,0.f,0.f}, aH1b = {0.f,0.f,0.f,0.f};
        {
          h8 af0 = ldfrag(ub + g4);
          h8 af1 = ldfrag(ub + 16 + g4);
          h8 af2 = ldfrag(ub + 32 + g4);
          h8 af3 = ldfrag(ub + 48 + g4);
          aH0a = MFMA16(af0, wh0[0], aH0a); aH1a = MFMA16(af0, wh1[0], aH1a);
          aH0b = MFMA16(af1, wh0[1], aH0b); aH1b = MFMA16(af1, wh1[1], aH1b);
          aH0a = MFMA16(af2, wh0[2], aH0a); aH1a = MFMA16(af2, wh1[2], aH1a);
          aH0b = MFMA16(af3, wh0[3], aH0b); aH1b = MFMA16(af3, wh1[3], aH1b);
        }
        float aH = selT1 ? (aH1a[0] + aH1b[0]) : (aH0a[0] + aH0b[0]);
        float mu = ss * (1.f / 128.f);
        float m2 = s2s * (1.f / 128.f);
        float rstd = rsq_fast(m2 - mu * mu + EPS_);
        float fl = (i > 0) ? 1.f : 0.f;
        float sc = fl * rstd;
        float pa = fmaf(sc, aH, fmaf(-sc * mu, cg, fl * cb)) + xcs;  // xcs has bhx
        float pt = tcs;                                              // tcs has btr
        float f   = tanh_fast(pa);
        float tau = taub + softplus_fast(pt);
        float hold = fl * fmaf((hcp - mu) * rstd, gr, ber);   // hn0[i-1][ct]
        float hc  = fmaf(f - hold, __builtin_amdgcn_rcpf(tau), hold);
        // publish hn0[i-1] (for B); slot (i-1)&3
        float hn2 = __shfl_xor(hold, 1);
        if (wlane) hn0p[(i + 3) & 3][widx] = as_u32(pkf16(hold, hn2));
        // publish raw hc0[i] (for own next step)
        float hc2 = __shfl_xor(hc, 1);
        if (wlane) h0p[i & 1][widx] = as_u32(pkf16(hc, hc2));
        // publish stats0[i] (per-wave slot)
        float v = (l & 32) ? hc * hc : hc;
        v = red16(v); v += __shfl_xor(v, 16);
        float v2 = __shfl_down(v, 32);             // lane0: (s, s2)
        if (l == 0) p0s[i & 3][wid] = make_float2(v, v2);
        hcp = hc;
        // pipelined x-GEMV for step i+1 (overlaps tail + barrier wait)
        {
          const uint32_t* xb = x4[(i + 1) & 3];
          f32x4 nX0 = {0.f,0.f,0.f,0.f}, nX1 = {0.f,0.f,0.f,0.f};
          f32x4 nT0 = {0.f,0.f,0.f,0.f}, nT1 = {0.f,0.f,0.f,0.f};
          #pragma unroll
          for (int m = 0; m < 2; ++m) {
            h8 xf = ldfrag(xb + m * 16 + g4);
            nX0 = MFMA16(xf, wx0[m], nX0);
            nX1 = MFMA16(xf, wx1[m], nX1);
            nT0 = MFMA16(xf, wt0[m], nT0);
            nT1 = MFMA16(xf, wt1[m], nT1);
          }
          xcs = (selT1 ? nX1[0] : nX0[0]) + bhx;
          tcs = (selT1 ? nT1[0] : nT0[0]) + btr;
        }
      }
      wg_barrier();
    }
  } else {
    // ========== group B: layer 1, step j = p-3; cols (wid-4)*32 .. +31 ==========
    const int c0 = (wid - 4) * 32 + (l & 15);
    const int ct = (wid - 4) * 32 + (l & 31);
    h8 vh0[4], vh1[4], vx0[4], vx1[4], vt0[4], vt1[4];
    float cAg, cAb;
    {
      float d1 = 0.f, d2 = 0.f, e1 = 0.f, e2 = 0.f;
      const float* p0 = Wh1 + c0 * H_ + g8;
      const float* p1 = Wh1 + (c0 + 16) * H_ + g8;
      const float* q0 = Wx1 + c0 * H_ + g8;
      const float* q1 = Wx1 + (c0 + 16) * H_ + g8;
      const float* r0 = Wt1 + c0 * H_ + g8;
      const float* r1 = Wt1 + (c0 + 16) * H_ + g8;
      #pragma unroll
      for (int m = 0; m < 4; ++m) {
        vh0[m] = packfrag_g(p0 + 32 * m, g1 + g8 + 32 * m, be1 + g8 + 32 * m, d1, d2);
        vh1[m] = packfrag_g(p1 + 32 * m, g1 + g8 + 32 * m, be1 + g8 + 32 * m, e1, e2);
        vx0[m] = packfrag(q0 + 32 * m); vx1[m] = packfrag(q1 + 32 * m);  // plain:
        vt0[m] = packfrag(r0 + 32 * m); vt1[m] = packfrag(r1 + 32 * m);  // input is hn0
      }
      d1 += __shfl_xor(d1, 16); d1 += __shfl_xor(d1, 32);
      d2 += __shfl_xor(d2, 16); d2 += __shfl_xor(d2, 32);
      e1 += __shfl_xor(e1, 16); e1 += __shfl_xor(e1, 32);
      e2 += __shfl_xor(e2, 16); e2 += __shfl_xor(e2, 32);
      cAg = selT1 ? e1 : d1; cAb = selT1 ? e2 : d2;
    }
    const float bhx = bh1[ct] + bx1[ct];
    const float btr = bt1[ct], taub = tau1[ct], gr = g1[ct], ber = be1[ct];
    const int  widx = (wid - 4) * 16 + ((l & 31) >> 1);
    const bool wlane = ((l & 33) == 0);
    const int  bw = wid - 4;

    float hcp = 0.f;
    float bcs = 0.f, tcs = 0.f;      // carried hn0-GEMV results (+biases)
    #pragma unroll 2
    for (int p = 0; p <= T_ + 2; ++p) {
      if (p >= 3) {
        const int j = p - 3;
        const float4* sp = (const float4*)&p1s[(j + 3) & 3][0];  // stats1[j-1]
        float4 sa = sp[0], sb = sp[1];
        float ss1 = (sa.x + sa.z) + (sb.x + sb.z);
        float s21 = (sa.y + sa.w) + (sb.y + sb.w);
        const uint32_t* u1b = h1p[(j + 1) & 1];    // hc1[j-1]
        // Wh1 chain: 2 independent 2-deep chains per tile
        f32x4 aA0a = {0.f,0.f,0.f,0.f}, aA0b = {0.f,0.f,0.f,0.f};
        f32x4 aA1a = {0.f,0.f,0.f,0.f}, aA1b = {0.f,0.f,0.f,0.f};
        {
          h8 af0 = ldfrag(u1b + g4);
          h8 af1 = ldfrag(u1b + 16 + g4);
          h8 af2 = ldfrag(u1b + 32 + g4);
          h8 af3 = ldfrag(u1b + 48 + g4);
          aA0a = MFMA16(af0, vh0[0], aA0a); aA1a = MFMA16(af0, vh1[0], aA1a);
          aA0b = MFMA16(af1, vh0[1], aA0b); aA1b = MFMA16(af1, vh1[1], aA1b);
          aA0a = MFMA16(af2, vh0[2], aA0a); aA1a = MFMA16(af2, vh1[2], aA1a);
          aA0b = MFMA16(af3, vh0[3], aA0b); aA1b = MFMA16(af3, vh1[3], aA1b);
        }
        float aA = selT1 ? (aA1a[0] + aA1b[0]) : (aA0a[0] + aA0b[0]);
        float mu1 = ss1 * (1.f / 128.f);
        float m21 = s21 * (1.f / 128.f);
        float rstd1 = rsq_fast(m21 - mu1 * mu1 + EPS_);
        float fl1 = (j > 0) ? 1.f : 0.f;
        float sc1 = fl1 * rstd1;
        float pa = fmaf(sc1, aA, fmaf(-sc1 * mu1, cAg, fl1 * cAb)) + bcs;  // bcs has bhx
        float pt = tcs;                                                    // tcs has btr
        float f   = tanh_fast(pa);
        float tau = taub + softplus_fast(pt);
        float hold = fl1 * fmaf((hcp - mu1) * rstd1, gr, ber);  // hn1[j-1][ct]
        float hc  = fmaf(f - hold, __builtin_amdgcn_rcpf(tau), hold);
        float hc2 = __shfl_xor(hc, 1);
        if (wlane) h1p[j & 1][widx] = as_u32(pkf16(hc, hc2));
        float v = (l & 32) ? hc * hc : hc;
        v = red16(v); v += __shfl_xor(v, 16);
        float v2 = __shfl_down(v, 32);
        if (l == 0) p1s[j & 3][bw] = make_float2(v, v2);
        hcp = hc;
      }
      // pipelined hn0-GEMV for step jn = p-2 (hn0[jn] published at phase
      // p-1, barrier-visible now); overlaps tail + barrier wait.
      if (p >= 2 && p <= T_ + 1) {
        const uint32_t* hnb = hn0p[(p - 2) & 3];
        f32x4 nB0 = {0.f,0.f,0.f,0.f}, nB1 = {0.f,0.f,0.f,0.f};
        f32x4 nT0 = {0.f,0.f,0.f,0.f}, nT1 = {0.f,0.f,0.f,0.f};
        #pragma unroll
        for (int m = 0; m < 4; ++m) {
          h8 f0 = ldfrag(hnb + m * 16 + g4);
          nB0 = MFMA16(f0, vx0[m], nB0);
          nB1 = MFMA16(f0, vx1[m], nB1);
          nT0 = MFMA16(f0, vt0[m], nT0);
          nT1 = MFMA16(f0, vt1[m], nT1);
        }
        bcs = (selT1 ? nB1[0] : nB0[0]) + bhx;
        tcs = (selT1 ? nT1[0] : nT0[0]) + btr;
      }
      wg_barrier();
    }
    // epilogue: hn1[T-1] = LN(hc1[T-1]) from stats1[T-1] (slot 3)
    {
      const float4* sp = (const float4*)&p1s[(T_ - 1) & 3][0];
      float4 sa = sp[0], sb = sp[1];
      float ss1 = (sa.x + sa.z) + (sb.x + sb.z);
      float s21 = (sa.y + sa.w) + (sb.y + sb.w);
      float mu1 = ss1 * (1.f / 128.f);
      float m21 = s21 * (1.f / 128.f);
      float rstd1 = rsq_fast(m21 - mu1 * mu1 + EPS_);
      float hn = fmaf((hcp - mu1) * rstd1, gr, ber);
      if (l < 32) out[b * H_ + ct] = hn;
    }
  }
}

extern "C" void kernel_launch(void* const* d_in, const int* in_sizes, int n_in,
                              void* d_out, int out_size, void* d_ws, size_t ws_size,
                              hipStream_t stream) {
  const float* x    = (const float*)d_in[0];
  const float* Wh0  = (const float*)d_in[1];
  const float* bh0  = (const float*)d_in[2];
  const float* Wx0  = (const float*)d_in[3];
  const float* bx0  = (const float*)d_in[4];
  const float* Wt0  = (const float*)d_in[5];
  const float* bt0  = (const float*)d_in[6];
  const float* tau0 = (const float*)d_in[7];
  const float* g0   = (const float*)d_in[8];
  const float* be0  = (const float*)d_in[9];
  const float* Wh1  = (const float*)d_in[10];
  const float* bh1  = (const float*)d_in[11];
  const float* Wx1  = (const float*)d_in[12];
  const float* bx1  = (const float*)d_in[13];
  const float* Wt1  = (const float*)d_in[14];
  const float* bt1  = (const float*)d_in[15];
  const float* tau1 = (const float*)d_in[16];
  const float* g1   = (const float*)d_in[17];
  const float* be1  = (const float*)d_in[18];
  float* out        = (float*)d_out;

  ltc_scan<<<B_, NT_, 0, stream>>>(x, Wh0, bh0, Wx0, bx0, Wt0, bt0, tau0, g0, be0,
                                   Wh1, bh1, Wx1, bx1, Wt1, bt1, tau1, g1, be1, out);
}